// Round 1
// baseline (327.940 us; speedup 1.0000x reference)
//
#include <hip/hip_runtime.h>
#include <math.h>

#define IMG 112
#define CIN 64
#define CH 256
#define PADW 114
#define IMG2 12544   // 112*112
#define NPIX 25088   // 2*112*112

typedef __bf16 bf16;
typedef __bf16 bf16x4 __attribute__((ext_vector_type(4)));
typedef __bf16 bf16x8 __attribute__((ext_vector_type(8)));
typedef float f32x4 __attribute__((ext_vector_type(4)));

__device__ __forceinline__ void gld_lds16(const void* g, void* l) {
    __builtin_amdgcn_global_load_lds(
        (const __attribute__((address_space(1))) void*)g,
        (__attribute__((address_space(3))) void*)l,
        16, 0, 0);
}

// ---------------- pad + NCHW f32 -> padded NHWC bf16 ----------------
__global__ __launch_bounds__(256) void pad_nhwc_kernel(const float* __restrict__ in, bf16* __restrict__ out) {
    int bi = blockIdx.x;            // 0 .. 2*112-1
    int b = bi / IMG, i = bi % IMG;
    __shared__ float lds[CIN * 113];  // stride 113 to break bank conflicts on transpose read
    const float* src = in + (size_t)b * CIN * IMG2 + (size_t)i * IMG;
    for (int t = threadIdx.x; t < CIN * IMG; t += 256) {
        int ci = t / IMG, j = t - ci * IMG;
        lds[ci * 113 + j] = src[(size_t)ci * IMG2 + j];
    }
    __syncthreads();
    bf16* dst = out + (((size_t)(b * PADW + (i + 1)) * PADW) + 1) * CIN;
    for (int t = threadIdx.x; t < CIN * IMG; t += 256) {
        int j = t / CIN, ci = t - j * CIN;
        dst[(size_t)j * CIN + ci] = (bf16)lds[ci * 113 + j];
    }
}

// ---------------- conv weights OIHW f32 -> [co][tap*64+ci] bf16 ----------------
__global__ __launch_bounds__(256) void convw_kernel(const float* __restrict__ w1, const float* __restrict__ w2,
                                                    bf16* __restrict__ o1, bf16* __restrict__ o2) {
    int idx = blockIdx.x * 256 + threadIdx.x;   // over 256*576
    if (idx >= CH * 576) return;
    int co = idx / 576, r = idx - co * 576;
    int tap = r >> 6, ci = r & 63;
    int src = co * 576 + ci * 9 + tap;
    o1[idx] = (bf16)w1[src];
    o2[idx] = (bf16)w2[src];
}

// ---------------- [K][N] f32 -> [N][K] bf16 (* scale) ----------------
__global__ __launch_bounds__(256) void transw_kernel(const float* __restrict__ in, bf16* __restrict__ out,
                                                     int K, int N, float scale) {
    int idx = blockIdx.x * 256 + threadIdx.x;   // over N*K
    if (idx >= N * K) return;
    int n = idx / K, k = idx - n * K;
    out[idx] = (bf16)(in[(size_t)k * N + n] * scale);
}

// ---------------- LayerNorm f32 -> 1 or 2 bf16 outputs ----------------
template <int NOUT>
__global__ __launch_bounds__(256) void ln_kernel(
    const float* __restrict__ x,
    const float* __restrict__ w0, const float* __restrict__ b0, bf16* __restrict__ o0,
    const float* __restrict__ w1, const float* __restrict__ b1, bf16* __restrict__ o1) {
    int row = blockIdx.x * 4 + (threadIdx.x >> 6);
    int lane = threadIdx.x & 63;
    const float* xr = x + (size_t)row * CH + lane * 4;
    f32x4 v = *(const f32x4*)xr;
    float s = v[0] + v[1] + v[2] + v[3];
    float ss = v[0] * v[0] + v[1] * v[1] + v[2] * v[2] + v[3] * v[3];
#pragma unroll
    for (int off = 32; off > 0; off >>= 1) {
        s += __shfl_xor(s, off);
        ss += __shfl_xor(ss, off);
    }
    float mean = s * (1.0f / CH);
    float rstd = rsqrtf(ss * (1.0f / CH) - mean * mean + 1e-5f);
    int c = lane * 4;
    {
        f32x4 w = *(const f32x4*)(w0 + c);
        f32x4 bb = *(const f32x4*)(b0 + c);
        bf16x4 o;
#pragma unroll
        for (int e = 0; e < 4; ++e) o[e] = (bf16)((v[e] - mean) * rstd * w[e] + bb[e]);
        *(bf16x4*)(o0 + (size_t)row * CH + c) = o;
    }
    if (NOUT == 2) {
        f32x4 w = *(const f32x4*)(w1 + c);
        f32x4 bb = *(const f32x4*)(b1 + c);
        bf16x4 o;
#pragma unroll
        for (int e = 0; e < 4; ++e) o[e] = (bf16)((v[e] - mean) * rstd * w[e] + bb[e]);
        *(bf16x4*)(o1 + (size_t)row * CH + c) = o;
    }
}

// ---------------- bf16 MFMA GEMM: out[M,N] = A[M,K] * Bt[N,K]^T (+epilogue) ----------------
// AMODE: 0 = dense A (lda=K), 1 = implicit conv patches from padded NHWC bf16 (K=576)
// EPI bits: 1=bias, 2=gelu, 4=add residual(f32,[M,N]), 8=store f32 dense, 16=store bf16 dense, 32=store NCHW f32
template <int AMODE, int EPI>
__global__ __launch_bounds__(256) void gemm_kernel(
    const bf16* __restrict__ A, const bf16* __restrict__ Bt,
    const float* __restrict__ bias, float biasScale,
    const float* __restrict__ res,
    float* __restrict__ outf, bf16* __restrict__ outb,
    int N, int K) {
    __shared__ __align__(16) bf16 As[128 * 64];
    __shared__ __align__(16) bf16 Bs[128 * 64];
    const int tid = threadIdx.x;
    const int wave = tid >> 6, lane = tid & 63;
    const int m0 = blockIdx.x * 128, n0 = blockIdx.y * 128;
    const int wm = wave >> 1, wn = wave & 1;
    const int fr = lane & 15, fq = lane >> 4;
    const int srow = wave * 32 + (lane >> 3);   // staging row (q=0)
    const int scol = (lane & 7) * 8;

    const bf16* aptr[4];
    const bf16* bptr[4];
#pragma unroll
    for (int q = 0; q < 4; ++q) {
        int arow = m0 + srow + q * 8;
        if (AMODE == 1) {
            int b = arow / IMG2;
            int rem = arow - b * IMG2;
            int i = rem / IMG, j = rem - i * IMG;
            aptr[q] = A + ((size_t)((b * PADW + i) * PADW + j)) * CIN + scol;
        } else {
            aptr[q] = A + (size_t)arow * K + scol;
        }
        bptr[q] = Bt + (size_t)(n0 + srow + q * 8) * K + scol;
    }

    f32x4 acc[4][4] = {};
    const int nk = K >> 6;
    for (int kt = 0; kt < nk; ++kt) {
        int aoff;
        if (AMODE == 1) {
            int di = kt / 3, dj = kt - di * 3;
            aoff = (di * PADW + dj) * CIN;
        } else {
            aoff = kt * 64;
        }
        int boff = kt * 64;
#pragma unroll
        for (int q = 0; q < 4; ++q) {
            gld_lds16(aptr[q] + aoff, &As[(wave * 4 + q) * 512]);
            gld_lds16(bptr[q] + boff, &Bs[(wave * 4 + q) * 512]);
        }
        __syncthreads();
#pragma unroll
        for (int ks = 0; ks < 2; ++ks) {
            bf16x8 af[4], bfr[4];
#pragma unroll
            for (int mi = 0; mi < 4; ++mi)
                af[mi] = *(const bf16x8*)&As[(wm * 64 + mi * 16 + fr) * 64 + ks * 32 + fq * 8];
#pragma unroll
            for (int ni = 0; ni < 4; ++ni)
                bfr[ni] = *(const bf16x8*)&Bs[(wn * 64 + ni * 16 + fr) * 64 + ks * 32 + fq * 8];
#pragma unroll
            for (int mi = 0; mi < 4; ++mi)
#pragma unroll
                for (int ni = 0; ni < 4; ++ni)
                    acc[mi][ni] = __builtin_amdgcn_mfma_f32_16x16x32_bf16(af[mi], bfr[ni], acc[mi][ni], 0, 0, 0);
        }
        __syncthreads();
    }

    // epilogue
#pragma unroll
    for (int mi = 0; mi < 4; ++mi) {
#pragma unroll
        for (int ni = 0; ni < 4; ++ni) {
            int col = n0 + wn * 64 + ni * 16 + fr;
            float bv = (EPI & 1) ? bias[col] * biasScale : 0.0f;
#pragma unroll
            for (int r = 0; r < 4; ++r) {
                int prow = m0 + wm * 64 + mi * 16 + fq * 4 + r;
                float x = acc[mi][ni][r] + bv;
                if (EPI & 2) x = 0.5f * x * (1.0f + erff(x * 0.70710678118f));
                if (EPI & 4) x += res[(size_t)prow * N + col];
                if (EPI & 8) outf[(size_t)prow * N + col] = x;
                if (EPI & 16) outb[(size_t)prow * N + col] = (bf16)x;
                if (EPI & 32) {
                    int b = prow / IMG2;
                    int rem = prow - b * IMG2;
                    int ii = rem / IMG, jj = rem - ii * IMG;
                    outf[(((size_t)b * CH + col) * IMG + ii) * IMG + jj] = x;
                }
            }
        }
    }
}

// ---------------- neighborhood attention (3x3 window, 8 heads, hd=32) ----------------
__global__ __launch_bounds__(256) void attn_kernel(const bf16* __restrict__ q, const bf16* __restrict__ kv,
                                                   const float* __restrict__ rpb, bf16* __restrict__ out) {
    int idx = blockIdx.x * 256 + threadIdx.x;   // 25088*8 total
    int h = idx & 7, p = idx >> 3;
    int b = p / IMG2;
    int rem = p - b * IMG2;
    int i = rem / IMG, j = rem - i * IMG;
    int si = i - 1; if (si < 0) si = 0; if (si > IMG - 3) si = IMG - 3;
    int sj = j - 1; if (sj < 0) sj = 0; if (sj > IMG - 3) sj = IMG - 3;
    int pi = i - si, pj = j - sj;

    float qv[32];
    {
        const bf16x8* qp = (const bf16x8*)(q + (size_t)p * CH + h * 32);
#pragma unroll
        for (int g = 0; g < 4; ++g) {
            bf16x8 t = qp[g];
#pragma unroll
            for (int e = 0; e < 8; ++e) qv[g * 8 + e] = (float)t[e];
        }
    }
    float logits[9];
#pragma unroll
    for (int a = 0; a < 3; ++a) {
#pragma unroll
        for (int bb = 0; bb < 3; ++bb) {
            int pn = (b * IMG + (si + a)) * IMG + (sj + bb);
            const bf16x8* kp = (const bf16x8*)(kv + (size_t)pn * 512 + h * 32);
            float s = 0.0f;
#pragma unroll
            for (int g = 0; g < 4; ++g) {
                bf16x8 t = kp[g];
#pragma unroll
                for (int e = 0; e < 8; ++e) s += qv[g * 8 + e] * (float)t[e];
            }
            logits[a * 3 + bb] = s + rpb[(h * 5 + (a - pi + 2)) * 5 + (bb - pj + 2)];
        }
    }
    float mx = logits[0];
#pragma unroll
    for (int n = 1; n < 9; ++n) mx = fmaxf(mx, logits[n]);
    float den = 0.0f;
#pragma unroll
    for (int n = 0; n < 9; ++n) { logits[n] = expf(logits[n] - mx); den += logits[n]; }
    float inv = 1.0f / den;
    float o[32] = {};
#pragma unroll
    for (int a = 0; a < 3; ++a) {
#pragma unroll
        for (int bb = 0; bb < 3; ++bb) {
            int pn = (b * IMG + (si + a)) * IMG + (sj + bb);
            float wgt = logits[a * 3 + bb] * inv;
            const bf16x8* vp = (const bf16x8*)(kv + (size_t)pn * 512 + 256 + h * 32);
#pragma unroll
            for (int g = 0; g < 4; ++g) {
                bf16x8 t = vp[g];
#pragma unroll
                for (int e = 0; e < 8; ++e) o[g * 8 + e] += wgt * (float)t[e];
            }
        }
    }
    bf16* op = out + (size_t)p * CH + h * 32;
#pragma unroll
    for (int g = 0; g < 4; ++g) {
        bf16x8 t;
#pragma unroll
        for (int e = 0; e < 8; ++e) t[e] = (bf16)o[g * 8 + e];
        *(bf16x8*)(op + g * 8) = t;
    }
}

extern "C" void kernel_launch(void* const* d_in, const int* in_sizes, int n_in,
                              void* d_out, int out_size, void* d_ws, size_t ws_size,
                              hipStream_t stream) {
    (void)in_sizes; (void)n_in; (void)out_size; (void)ws_size;
    const float* xq    = (const float*)d_in[0];
    const float* xkv   = (const float*)d_in[1];
    const float* c1w   = (const float*)d_in[2];
    const float* c1b   = (const float*)d_in[3];
    const float* c3w   = (const float*)d_in[4];
    const float* c3b   = (const float*)d_in[5];
    const float* ln1w  = (const float*)d_in[6];
    const float* ln1b  = (const float*)d_in[7];
    const float* ln10w = (const float*)d_in[8];
    const float* ln10b = (const float*)d_in[9];
    const float* ln3w  = (const float*)d_in[10];
    const float* ln3b  = (const float*)d_in[11];
    const float* wq    = (const float*)d_in[12];
    const float* bq    = (const float*)d_in[13];
    const float* wkv   = (const float*)d_in[14];
    const float* bkv   = (const float*)d_in[15];
    const float* rpb   = (const float*)d_in[16];
    const float* wp    = (const float*)d_in[17];
    const float* bp    = (const float*)d_in[18];
    const float* f1w   = (const float*)d_in[19];
    const float* f1b   = (const float*)d_in[20];
    const float* f2w   = (const float*)d_in[21];
    const float* f2b   = (const float*)d_in[22];
    float* out = (float*)d_out;

    char* ws = (char*)d_ws;
    bf16*  PADQ  = (bf16*)(ws + 0);            // 3,326,976 B
    bf16*  PADKV = (bf16*)(ws + 3326976);      // 3,326,976
    bf16*  CW1   = (bf16*)(ws + 6653952);      //   294,912
    bf16*  CW2   = (bf16*)(ws + 6948864);      //   294,912
    bf16*  WQT   = (bf16*)(ws + 7243776);      //   131,072
    bf16*  WKVT  = (bf16*)(ws + 7374848);      //   262,144
    bf16*  WPT   = (bf16*)(ws + 7636992);      //   131,072
    bf16*  WF1   = (bf16*)(ws + 7768064);      //   262,144
    bf16*  WF2   = (bf16*)(ws + 8030208);      //   262,144
    float* X1    = (float*)(ws + 8292352);     // 25,690,112
    bf16*  KV    = (bf16*)(ws + 8292352);      // reuse X1 (dead after LN1)
    float* X3    = (float*)(ws + 33982464);    // 25,690,112
    bf16*  QN    = (bf16*)(ws + 59672576);     // 12,845,056
    bf16*  M1    = (bf16*)(ws + 59672576);     // reuse QN+KVN (dead after q/kv gemms)
    bf16*  KVN   = (bf16*)(ws + 72517632);     // 12,845,056
    bf16*  Q     = (bf16*)(ws + 85362688);     // 12,845,056
    bf16*  H     = (bf16*)(ws + 85362688);     // reuse Q (dead after attn)
    bf16*  AO    = (bf16*)(ws + 98207744);     // 12,845,056
    float* ATT   = (float*)(ws + 111052800);   // 25,690,112  -> total 136,742,912

    const float SC = 0.17677669529663687f;  // 32^-0.5

    hipMemsetAsync(PADQ, 0, 6653952, stream);  // both padded images
    pad_nhwc_kernel<<<224, 256, 0, stream>>>(xq, PADQ);
    pad_nhwc_kernel<<<224, 256, 0, stream>>>(xkv, PADKV);
    convw_kernel<<<576, 256, 0, stream>>>(c1w, c3w, CW1, CW2);
    transw_kernel<<<256, 256, 0, stream>>>(wq, WQT, 256, 256, SC);
    transw_kernel<<<512, 256, 0, stream>>>(wkv, WKVT, 256, 512, 1.0f);
    transw_kernel<<<256, 256, 0, stream>>>(wp, WPT, 256, 256, 1.0f);
    transw_kernel<<<512, 256, 0, stream>>>(f1w, WF1, 256, 512, 1.0f);
    transw_kernel<<<512, 256, 0, stream>>>(f2w, WF2, 512, 256, 1.0f);

    dim3 g2(196, 2), g4(196, 4);
    // conv1 -> x1 (f32), conv3 -> x3 (f32)
    gemm_kernel<1, 1 | 8><<<g2, 256, 0, stream>>>(PADQ, CW1, c1b, 1.0f, nullptr, X1, nullptr, 256, 576);
    gemm_kernel<1, 1 | 8><<<g2, 256, 0, stream>>>(PADKV, CW2, c3b, 1.0f, nullptr, X3, nullptr, 256, 576);
    // LN(x1) -> qn, kvn (bf16)
    ln_kernel<2><<<6272, 256, 0, stream>>>(X1, ln1w, ln1b, QN, ln10w, ln10b, KVN);
    // q = (qn@wq + bq)*scale (scale folded into WQT and bias), kv = kvn@wkv + bkv
    gemm_kernel<0, 1 | 16><<<g2, 256, 0, stream>>>(QN, WQT, bq, SC, nullptr, nullptr, Q, 256, 256);
    gemm_kernel<0, 1 | 16><<<g4, 256, 0, stream>>>(KVN, WKVT, bkv, 1.0f, nullptr, nullptr, KV, 512, 256);
    // neighborhood attention
    attn_kernel<<<784, 256, 0, stream>>>(Q, KV, rpb, AO);
    // att = ao@wp + bp + x3 (f32)
    gemm_kernel<0, 1 | 4 | 8><<<g2, 256, 0, stream>>>(AO, WPT, bp, 1.0f, X3, ATT, nullptr, 256, 256);
    // h = LN(att) (bf16)
    ln_kernel<1><<<6272, 256, 0, stream>>>(ATT, ln3w, ln3b, H, nullptr, nullptr, nullptr);
    // m1 = gelu(h@fc1 + b) (bf16)
    gemm_kernel<0, 1 | 2 | 16><<<g4, 256, 0, stream>>>(H, WF1, f1b, 1.0f, nullptr, nullptr, M1, 512, 256);
    // out = (m1@fc2 + b + att) transposed to NCHW (f32)
    gemm_kernel<0, 1 | 4 | 32><<<g2, 256, 0, stream>>>(M1, WF2, f2b, 1.0f, ATT, out, nullptr, 256, 512);
}

// Round 2
// 298.332 us; speedup vs baseline: 1.0992x; 1.0992x over previous
//
#include <hip/hip_runtime.h>
#include <math.h>

#define IMG 112
#define CIN 64
#define CH 256
#define PADW 114
#define IMG2 12544   // 112*112
#define NPIX 25088   // 2*112*112

typedef __bf16 bf16;
typedef __bf16 bf16x4 __attribute__((ext_vector_type(4)));
typedef __bf16 bf16x8 __attribute__((ext_vector_type(8)));
typedef float f32x4 __attribute__((ext_vector_type(4)));

__device__ __forceinline__ void gld_lds16(const void* g, void* l) {
    __builtin_amdgcn_global_load_lds(
        (const __attribute__((address_space(1))) void*)g,
        (__attribute__((address_space(3))) void*)l,
        16, 0, 0);
}

#define VMCNT0() asm volatile("s_waitcnt vmcnt(0)" ::: "memory")
#define BAR() __builtin_amdgcn_s_barrier()

// ---------------- pad + NCHW f32 -> padded NHWC bf16 ----------------
__global__ __launch_bounds__(256) void pad_nhwc_kernel(const float* __restrict__ in, bf16* __restrict__ out) {
    int bi = blockIdx.x;            // 0 .. 2*112-1
    int b = bi / IMG, i = bi % IMG;
    __shared__ float lds[CIN * 113];
    const float* src = in + (size_t)b * CIN * IMG2 + (size_t)i * IMG;
    for (int t = threadIdx.x; t < CIN * IMG; t += 256) {
        int ci = t / IMG, j = t - ci * IMG;
        lds[ci * 113 + j] = src[(size_t)ci * IMG2 + j];
    }
    __syncthreads();
    bf16* dst = out + (((size_t)(b * PADW + (i + 1)) * PADW) + 1) * CIN;
    for (int t = threadIdx.x; t < CIN * IMG; t += 256) {
        int j = t / CIN, ci = t - j * CIN;
        dst[(size_t)j * CIN + ci] = (bf16)lds[ci * 113 + j];
    }
}

// ---------------- conv weights OIHW f32 -> [co][tap*64+ci] bf16 ----------------
__global__ __launch_bounds__(256) void convw_kernel(const float* __restrict__ w1, const float* __restrict__ w2,
                                                    bf16* __restrict__ o1, bf16* __restrict__ o2) {
    int idx = blockIdx.x * 256 + threadIdx.x;
    if (idx >= CH * 576) return;
    int co = idx / 576, r = idx - co * 576;
    int tap = r >> 6, ci = r & 63;
    int src = co * 576 + ci * 9 + tap;
    o1[idx] = (bf16)w1[src];
    o2[idx] = (bf16)w2[src];
}

// ---------------- [K][N] f32 -> [N][K] bf16 (* scale) ----------------
__global__ __launch_bounds__(256) void transw_kernel(const float* __restrict__ in, bf16* __restrict__ out,
                                                     int K, int N, float scale) {
    int idx = blockIdx.x * 256 + threadIdx.x;
    if (idx >= N * K) return;
    int n = idx / K, k = idx - n * K;
    out[idx] = (bf16)(in[(size_t)k * N + n] * scale);
}

// ---------------- LayerNorm f32 -> 1 or 2 bf16 outputs ----------------
template <int NOUT>
__global__ __launch_bounds__(256) void ln_kernel(
    const float* __restrict__ x,
    const float* __restrict__ w0, const float* __restrict__ b0, bf16* __restrict__ o0,
    const float* __restrict__ w1, const float* __restrict__ b1, bf16* __restrict__ o1) {
    int row = blockIdx.x * 4 + (threadIdx.x >> 6);
    int lane = threadIdx.x & 63;
    const float* xr = x + (size_t)row * CH + lane * 4;
    f32x4 v = *(const f32x4*)xr;
    float s = v[0] + v[1] + v[2] + v[3];
    float ss = v[0] * v[0] + v[1] * v[1] + v[2] * v[2] + v[3] * v[3];
#pragma unroll
    for (int off = 32; off > 0; off >>= 1) {
        s += __shfl_xor(s, off);
        ss += __shfl_xor(ss, off);
    }
    float mean = s * (1.0f / CH);
    float rstd = rsqrtf(ss * (1.0f / CH) - mean * mean + 1e-5f);
    int c = lane * 4;
    {
        f32x4 w = *(const f32x4*)(w0 + c);
        f32x4 bb = *(const f32x4*)(b0 + c);
        bf16x4 o;
#pragma unroll
        for (int e = 0; e < 4; ++e) o[e] = (bf16)((v[e] - mean) * rstd * w[e] + bb[e]);
        *(bf16x4*)(o0 + (size_t)row * CH + c) = o;
    }
    if (NOUT == 2) {
        f32x4 w = *(const f32x4*)(w1 + c);
        f32x4 bb = *(const f32x4*)(b1 + c);
        bf16x4 o;
#pragma unroll
        for (int e = 0; e < 4; ++e) o[e] = (bf16)((v[e] - mean) * rstd * w[e] + bb[e]);
        *(bf16x4*)(o1 + (size_t)row * CH + c) = o;
    }
}

// ---------------- bf16 MFMA GEMM: out[M,N] = A[M,K] * Bt[N,K]^T (+epilogue) ----------------
// 64x64 tile, BK=64, 4 waves (2x2, 32x32/wave), double-buffered 2-phase pipeline,
// XOR-swizzled LDS (chunk ^= row&7) via pre-swizzled global source (rule #21).
// AMODE: 0 = dense A (lda=K), 1 = implicit conv patches from padded NHWC bf16 (K=576)
// EPI bits: 1=bias, 2=gelu, 4=add residual(f32,[M,N]), 8=store f32 dense, 16=store bf16 dense, 32=store NCHW f32
template <int AMODE, int EPI>
__global__ __launch_bounds__(256, 5) void gemm_kernel(
    const bf16* __restrict__ A, const bf16* __restrict__ Bt,
    const float* __restrict__ bias, float biasScale,
    const float* __restrict__ res,
    float* __restrict__ outf, bf16* __restrict__ outb,
    int N, int K) {
    __shared__ __align__(16) bf16 As[2][64 * 64];
    __shared__ __align__(16) bf16 Bs[2][64 * 64];
    const int tid = threadIdx.x;
    const int wave = tid >> 6, lane = tid & 63;
    const int m0 = blockIdx.x * 64, n0 = blockIdx.y * 64;
    const int wm = wave >> 1, wn = wave & 1;
    const int fr = lane & 15, fq = lane >> 4;

    // staging: each wave owns 16 rows of As and 16 rows of Bs per K-step (2 gld_lds each)
    const int srow = (lane >> 3);               // 0..7 within the 8-row group
    const int swzc = (lane & 7) ^ srow;         // inverse-swizzled source chunk
    const int scol = swzc * 8;                  // element offset within 64-elem row

    const bf16* aptr[2];
    const bf16* bptr[2];
#pragma unroll
    for (int q = 0; q < 2; ++q) {
        int arow = m0 + wave * 16 + q * 8 + srow;
        if (AMODE == 1) {
            int b = arow / IMG2;
            int rem = arow - b * IMG2;
            int i = rem / IMG, j = rem - i * IMG;
            aptr[q] = A + ((size_t)((b * PADW + i) * PADW + j)) * CIN + scol;
        } else {
            aptr[q] = A + (size_t)arow * K + scol;
        }
        bptr[q] = Bt + (size_t)(n0 + wave * 16 + q * 8 + srow) * K + scol;
    }

    auto STAGE = [&](int bufi, int kt) {
        int aoff;
        if (AMODE == 1) {
            int di = kt / 3, dj = kt - di * 3;
            aoff = (di * PADW + dj) * CIN;
        } else {
            aoff = kt * 64;
        }
        int boff = kt * 64;
        gld_lds16(aptr[0] + aoff, &As[bufi][(wave * 16 + 0) * 64]);
        gld_lds16(aptr[1] + aoff, &As[bufi][(wave * 16 + 8) * 64]);
        gld_lds16(bptr[0] + boff, &Bs[bufi][(wave * 16 + 0) * 64]);
        gld_lds16(bptr[1] + boff, &Bs[bufi][(wave * 16 + 8) * 64]);
    };

    f32x4 acc[2][2] = {};
    const int sw = fr & 7;                       // row&7 for all fragment rows
    const int aR[2] = { (wm * 32 + fr) * 64, (wm * 32 + 16 + fr) * 64 };
    const int bR[2] = { (wn * 32 + fr) * 64, (wn * 32 + 16 + fr) * 64 };

    auto COMPUTE = [&](int bufi) {
#pragma unroll
        for (int ks = 0; ks < 2; ++ks) {
            int ch = (ks * 4 + fq) ^ sw;         // swizzled chunk
            bf16x8 af[2], bv[2];
#pragma unroll
            for (int mi = 0; mi < 2; ++mi) af[mi] = *(const bf16x8*)&As[bufi][aR[mi] + ch * 8];
#pragma unroll
            for (int ni = 0; ni < 2; ++ni) bv[ni] = *(const bf16x8*)&Bs[bufi][bR[ni] + ch * 8];
#pragma unroll
            for (int mi = 0; mi < 2; ++mi)
#pragma unroll
                for (int ni = 0; ni < 2; ++ni)
                    acc[mi][ni] = __builtin_amdgcn_mfma_f32_16x16x32_bf16(af[mi], bv[ni], acc[mi][ni], 0, 0, 0);
        }
    };

    const int nk = K >> 6;
    // prologue
    STAGE(0, 0);
    VMCNT0();
    BAR();
    int cur = 0;
    for (int kt = 0; kt < nk - 1; ++kt) {
        STAGE(cur ^ 1, kt + 1);   // issue next-tile loads first (overlap with compute)
        COMPUTE(cur);
        VMCNT0();
        BAR();
        cur ^= 1;
    }
    COMPUTE(cur);                 // last tile, no prefetch

    // epilogue
#pragma unroll
    for (int mi = 0; mi < 2; ++mi) {
#pragma unroll
        for (int ni = 0; ni < 2; ++ni) {
            int col = n0 + wn * 32 + ni * 16 + fr;
            float bv = (EPI & 1) ? bias[col] * biasScale : 0.0f;
#pragma unroll
            for (int r = 0; r < 4; ++r) {
                int prow = m0 + wm * 32 + mi * 16 + fq * 4 + r;
                float x = acc[mi][ni][r] + bv;
                if (EPI & 2) x = 0.5f * x * (1.0f + erff(x * 0.70710678118f));
                if (EPI & 4) x += res[(size_t)prow * N + col];
                if (EPI & 8) outf[(size_t)prow * N + col] = x;
                if (EPI & 16) outb[(size_t)prow * N + col] = (bf16)x;
                if (EPI & 32) {
                    int b = prow / IMG2;
                    int rem = prow - b * IMG2;
                    int ii = rem / IMG, jj = rem - ii * IMG;
                    outf[(((size_t)b * CH + col) * IMG + ii) * IMG + jj] = x;
                }
            }
        }
    }
}

// ---------------- neighborhood attention (3x3 window, 8 heads, hd=32) ----------------
__global__ __launch_bounds__(256) void attn_kernel(const bf16* __restrict__ q, const bf16* __restrict__ kv,
                                                   const float* __restrict__ rpb, bf16* __restrict__ out) {
    int idx = blockIdx.x * 256 + threadIdx.x;   // 25088*8 total
    int h = idx & 7, p = idx >> 3;
    int b = p / IMG2;
    int rem = p - b * IMG2;
    int i = rem / IMG, j = rem - i * IMG;
    int si = i - 1; if (si < 0) si = 0; if (si > IMG - 3) si = IMG - 3;
    int sj = j - 1; if (sj < 0) sj = 0; if (sj > IMG - 3) sj = IMG - 3;
    int pi = i - si, pj = j - sj;

    float qv[32];
    {
        const bf16x8* qp = (const bf16x8*)(q + (size_t)p * CH + h * 32);
#pragma unroll
        for (int g = 0; g < 4; ++g) {
            bf16x8 t = qp[g];
#pragma unroll
            for (int e = 0; e < 8; ++e) qv[g * 8 + e] = (float)t[e];
        }
    }
    float logits[9];
#pragma unroll
    for (int a = 0; a < 3; ++a) {
#pragma unroll
        for (int bb = 0; bb < 3; ++bb) {
            int pn = (b * IMG + (si + a)) * IMG + (sj + bb);
            const bf16x8* kp = (const bf16x8*)(kv + (size_t)pn * 512 + h * 32);
            float s = 0.0f;
#pragma unroll
            for (int g = 0; g < 4; ++g) {
                bf16x8 t = kp[g];
#pragma unroll
                for (int e = 0; e < 8; ++e) s += qv[g * 8 + e] * (float)t[e];
            }
            logits[a * 3 + bb] = s + rpb[(h * 5 + (a - pi + 2)) * 5 + (bb - pj + 2)];
        }
    }
    float mx = logits[0];
#pragma unroll
    for (int n = 1; n < 9; ++n) mx = fmaxf(mx, logits[n]);
    float den = 0.0f;
#pragma unroll
    for (int n = 0; n < 9; ++n) { logits[n] = expf(logits[n] - mx); den += logits[n]; }
    float inv = 1.0f / den;
    float o[32] = {};
#pragma unroll
    for (int a = 0; a < 3; ++a) {
#pragma unroll
        for (int bb = 0; bb < 3; ++bb) {
            int pn = (b * IMG + (si + a)) * IMG + (sj + bb);
            float wgt = logits[a * 3 + bb] * inv;
            const bf16x8* vp = (const bf16x8*)(kv + (size_t)pn * 512 + 256 + h * 32);
#pragma unroll
            for (int g = 0; g < 4; ++g) {
                bf16x8 t = vp[g];
#pragma unroll
                for (int e = 0; e < 8; ++e) o[g * 8 + e] += wgt * (float)t[e];
            }
        }
    }
    bf16* op = out + (size_t)p * CH + h * 32;
#pragma unroll
    for (int g = 0; g < 4; ++g) {
        bf16x8 t;
#pragma unroll
        for (int e = 0; e < 8; ++e) t[e] = (bf16)o[g * 8 + e];
        *(bf16x8*)(op + g * 8) = t;
    }
}

extern "C" void kernel_launch(void* const* d_in, const int* in_sizes, int n_in,
                              void* d_out, int out_size, void* d_ws, size_t ws_size,
                              hipStream_t stream) {
    (void)in_sizes; (void)n_in; (void)out_size; (void)ws_size;
    const float* xq    = (const float*)d_in[0];
    const float* xkv   = (const float*)d_in[1];
    const float* c1w   = (const float*)d_in[2];
    const float* c1b   = (const float*)d_in[3];
    const float* c3w   = (const float*)d_in[4];
    const float* c3b   = (const float*)d_in[5];
    const float* ln1w  = (const float*)d_in[6];
    const float* ln1b  = (const float*)d_in[7];
    const float* ln10w = (const float*)d_in[8];
    const float* ln10b = (const float*)d_in[9];
    const float* ln3w  = (const float*)d_in[10];
    const float* ln3b  = (const float*)d_in[11];
    const float* wq    = (const float*)d_in[12];
    const float* bq    = (const float*)d_in[13];
    const float* wkv   = (const float*)d_in[14];
    const float* bkv   = (const float*)d_in[15];
    const float* rpb   = (const float*)d_in[16];
    const float* wp    = (const float*)d_in[17];
    const float* bp    = (const float*)d_in[18];
    const float* f1w   = (const float*)d_in[19];
    const float* f1b   = (const float*)d_in[20];
    const float* f2w   = (const float*)d_in[21];
    const float* f2b   = (const float*)d_in[22];
    float* out = (float*)d_out;

    char* ws = (char*)d_ws;
    bf16*  PADQ  = (bf16*)(ws + 0);            // 3,326,976 B
    bf16*  PADKV = (bf16*)(ws + 3326976);      // 3,326,976
    bf16*  CW1   = (bf16*)(ws + 6653952);      //   294,912
    bf16*  CW2   = (bf16*)(ws + 6948864);      //   294,912
    bf16*  WQT   = (bf16*)(ws + 7243776);      //   131,072
    bf16*  WKVT  = (bf16*)(ws + 7374848);      //   262,144
    bf16*  WPT   = (bf16*)(ws + 7636992);      //   131,072
    bf16*  WF1   = (bf16*)(ws + 7768064);      //   262,144
    bf16*  WF2   = (bf16*)(ws + 8030208);      //   262,144
    float* X1    = (float*)(ws + 8292352);     // 25,690,112
    bf16*  KV    = (bf16*)(ws + 8292352);      // reuse X1 (dead after LN1)
    float* X3    = (float*)(ws + 33982464);    // 25,690,112
    bf16*  QN    = (bf16*)(ws + 59672576);     // 12,845,056
    bf16*  M1    = (bf16*)(ws + 59672576);     // reuse QN+KVN (dead after q/kv gemms)
    bf16*  KVN   = (bf16*)(ws + 72517632);     // 12,845,056
    bf16*  Q     = (bf16*)(ws + 85362688);     // 12,845,056
    bf16*  H     = (bf16*)(ws + 85362688);     // reuse Q (dead after attn)
    bf16*  AO    = (bf16*)(ws + 98207744);     // 12,845,056
    float* ATT   = (float*)(ws + 111052800);   // 25,690,112  -> total 136,742,912

    const float SC = 0.17677669529663687f;  // 32^-0.5

    hipMemsetAsync(PADQ, 0, 6653952, stream);  // both padded images
    pad_nhwc_kernel<<<224, 256, 0, stream>>>(xq, PADQ);
    pad_nhwc_kernel<<<224, 256, 0, stream>>>(xkv, PADKV);
    convw_kernel<<<576, 256, 0, stream>>>(c1w, c3w, CW1, CW2);
    transw_kernel<<<256, 256, 0, stream>>>(wq, WQT, 256, 256, SC);
    transw_kernel<<<512, 256, 0, stream>>>(wkv, WKVT, 256, 512, 1.0f);
    transw_kernel<<<256, 256, 0, stream>>>(wp, WPT, 256, 256, 1.0f);
    transw_kernel<<<512, 256, 0, stream>>>(f1w, WF1, 256, 512, 1.0f);
    transw_kernel<<<512, 256, 0, stream>>>(f2w, WF2, 512, 256, 1.0f);

    dim3 g4(392, 4), g8(392, 8);
    // conv1 -> x1 (f32), conv3 -> x3 (f32)
    gemm_kernel<1, 1 | 8><<<g4, 256, 0, stream>>>(PADQ, CW1, c1b, 1.0f, nullptr, X1, nullptr, 256, 576);
    gemm_kernel<1, 1 | 8><<<g4, 256, 0, stream>>>(PADKV, CW2, c3b, 1.0f, nullptr, X3, nullptr, 256, 576);
    // LN(x1) -> qn, kvn (bf16)
    ln_kernel<2><<<6272, 256, 0, stream>>>(X1, ln1w, ln1b, QN, ln10w, ln10b, KVN);
    // q = (qn@wq + bq)*scale (scale folded into WQT and bias), kv = kvn@wkv + bkv
    gemm_kernel<0, 1 | 16><<<g4, 256, 0, stream>>>(QN, WQT, bq, SC, nullptr, nullptr, Q, 256, 256);
    gemm_kernel<0, 1 | 16><<<g8, 256, 0, stream>>>(KVN, WKVT, bkv, 1.0f, nullptr, nullptr, KV, 512, 256);
    // neighborhood attention
    attn_kernel<<<784, 256, 0, stream>>>(Q, KV, rpb, AO);
    // att = ao@wp + bp + x3 (f32)
    gemm_kernel<0, 1 | 4 | 8><<<g4, 256, 0, stream>>>(AO, WPT, bp, 1.0f, X3, ATT, nullptr, 256, 256);
    // h = LN(att) (bf16)
    ln_kernel<1><<<6272, 256, 0, stream>>>(ATT, ln3w, ln3b, H, nullptr, nullptr, nullptr);
    // m1 = gelu(h@fc1 + b) (bf16)
    gemm_kernel<0, 1 | 2 | 16><<<g8, 256, 0, stream>>>(H, WF1, f1b, 1.0f, nullptr, nullptr, M1, 512, 256);
    // out = (m1@fc2 + b + att) transposed to NCHW (f32)
    gemm_kernel<0, 1 | 4 | 32><<<g4, 256, 0, stream>>>(M1, WF2, f2b, 1.0f, ATT, out, nullptr, 256, 512);
}

// Round 5
// 291.102 us; speedup vs baseline: 1.1265x; 1.0248x over previous
//
#include <hip/hip_runtime.h>
#include <math.h>

#define IMG 112
#define CIN 64
#define CH 256
#define PADW 114
#define IMG2 12544   // 112*112
#define NPIX 25088   // 2*112*112
#define SCQ 0.17677669529663687f

typedef __bf16 bf16;
typedef __bf16 bf16x8 __attribute__((ext_vector_type(8)));
typedef float f32x4 __attribute__((ext_vector_type(4)));

__device__ __forceinline__ void gld_lds16(const void* g, void* l) {
    __builtin_amdgcn_global_load_lds(
        (const __attribute__((address_space(1))) void*)g,
        (__attribute__((address_space(3))) void*)l,
        16, 0, 0);
}
#define VMCNT0() asm volatile("s_waitcnt vmcnt(0)" ::: "memory")
#define BAR() __builtin_amdgcn_s_barrier()

// ---------------- prep: pad images (+zero borders) + all weight transposes ----------------
__global__ __launch_bounds__(256) void prep_kernel(
    const float* __restrict__ xq, const float* __restrict__ xkv,
    bf16* __restrict__ padq, bf16* __restrict__ padkv,
    const float* __restrict__ c1w, const float* __restrict__ c3w,
    bf16* __restrict__ cw1, bf16* __restrict__ cw2,
    const float* __restrict__ wq, bf16* __restrict__ wqt,
    const float* __restrict__ wkv, bf16* __restrict__ wkvt,
    const float* __restrict__ wp, bf16* __restrict__ wpt,
    const float* __restrict__ f1w, bf16* __restrict__ wf1,
    const float* __restrict__ f2w, bf16* __restrict__ wf2) {
    int bid = blockIdx.x, tid = threadIdx.x;
    __shared__ float lds[CIN * 113];
    if (bid < 448) {
        const float* in = (bid < 224) ? xq : xkv;
        bf16* out = (bid < 224) ? padq : padkv;
        int bi = (bid < 224) ? bid : bid - 224;   // FIX: was `bid & 223` (223 is not a pow2 mask)
        int b = bi / IMG, i = bi % IMG;
        const float* src = in + (size_t)b * CIN * IMG2 + (size_t)i * IMG;
        for (int t = tid; t < CIN * IMG; t += 256) {
            int ci = t / IMG, j = t - ci * IMG;
            lds[ci * 113 + j] = src[(size_t)ci * IMG2 + j];
        }
        __syncthreads();
        bf16* dst = out + (((size_t)(b * PADW + (i + 1)) * PADW) + 1) * CIN;
        for (int t = tid; t < CIN * IMG; t += 256) {
            int j = t / CIN, ci = t - j * CIN;
            dst[(size_t)j * CIN + ci] = (bf16)lds[ci * 113 + j];
        }
        // border zeroing: cols 0 and 113 of this padded row
        bf16* rowbase = out + ((size_t)(b * PADW + (i + 1)) * PADW) * CIN;
        if (tid < 128) rowbase[(tid >> 6 ? 113 * CIN : 0) + (tid & 63)] = (bf16)0.0f;
        if (i == 0)
            for (int t = tid; t < PADW * CIN; t += 256)
                out[((size_t)(b * PADW + 0) * PADW) * CIN + t] = (bf16)0.0f;
        if (i == IMG - 1)
            for (int t = tid; t < PADW * CIN; t += 256)
                out[((size_t)(b * PADW + 113) * PADW) * CIN + t] = (bf16)0.0f;
    } else if (bid < 1024) {
        int idx = (bid - 448) * 256 + tid;   // 147456 = 576 blocks
        int co = idx / 576, r = idx - co * 576;
        int tap = r >> 6, ci = r & 63;
        int src = co * 576 + ci * 9 + tap;
        cw1[idx] = (bf16)c1w[src];
        cw2[idx] = (bf16)c3w[src];
    } else {
        int off = (bid - 1024) * 256 + tid;  // 524288 = 2048 blocks
        const float* in; bf16* out; int K, N; float sc = 1.0f; int base;
        if (off < 65536)       { in = wq;  out = wqt;  K = 256; N = 256; sc = SCQ; base = 0; }
        else if (off < 196608) { in = wkv; out = wkvt; K = 256; N = 512; base = 65536; }
        else if (off < 262144) { in = wp;  out = wpt;  K = 256; N = 256; base = 196608; }
        else if (off < 393216) { in = f1w; out = wf1;  K = 256; N = 512; base = 262144; }
        else                   { in = f2w; out = wf2;  K = 512; N = 256; base = 393216; }
        int idx = off - base;
        int n = idx / K, k = idx - n * K;
        out[idx] = (bf16)(in[(size_t)k * N + n] * sc);
    }
}

// ---------------- fused GEMM core: 64x256 tile, BK=64, 4 waves (2x2 -> 32x128/wave) ----------------
// MODE: 0=dense bf16 out; 1=LN->two bf16 outs; 2=res+out0(raw)+LN->out1; 3=gelu->bf16; 4=f32 NCHW + res
#define M_DENSE 0
#define M_LN2   1
#define M_WPLN  2
#define M_GELU  3
#define M_NCHW  4

template <int AMODE, int MODE>
__device__ __forceinline__ void gemm_core(
    char* sm,
    const bf16* __restrict__ A, const bf16* __restrict__ B,
    const float* __restrict__ bias, float bscale,
    const bf16* __restrict__ res,
    bf16* __restrict__ out0, int ldo0,
    bf16* __restrict__ out1, float* __restrict__ outf,
    const float* __restrict__ lnw0, const float* __restrict__ lnb0,
    const float* __restrict__ lnw1, const float* __restrict__ lnb1,
    int K) {
    bf16* As = (bf16*)sm;              // [2][64*64]   16 KB
    bf16* Bs = (bf16*)(sm + 16384);    // [2][256*64]  64 KB
    float* lnb = (float*)sm;           // [2][2][64] reused after barrier (1 KB)
    float* T = (float*)(sm + 2048);    // [64][257] f32 transpose buffer (65.8 KB)

    const int tid = threadIdx.x;
    const int wave = tid >> 6, lane = tid & 63;
    const int m0 = blockIdx.x * 64;
    const int wm = wave >> 1, wn = wave & 1;
    const int fr = lane & 15, fq = lane >> 4;
    const int srow = lane >> 3;
    const int scol = ((lane & 7) ^ srow) * 8;

    const bf16* aptr[2];
#pragma unroll
    for (int q = 0; q < 2; ++q) {
        int arow = m0 + wave * 16 + q * 8 + srow;
        if (AMODE == 1) {
            int b = arow / IMG2;
            int rem = arow - b * IMG2;
            int i = rem / IMG, j = rem - i * IMG;
            aptr[q] = A + ((size_t)((b * PADW + i) * PADW + j)) * CIN + scol;
        } else {
            aptr[q] = A + (size_t)arow * K + scol;
        }
    }
    const bf16* bptr0 = B + (size_t)(wave * 64 + srow) * K + scol;

    auto STAGE = [&](int bi, int kt) {
        int aoff = (AMODE == 1) ? ((kt / 3) * PADW + (kt - (kt / 3) * 3)) * CIN : kt * 64;
        int boff = kt * 64;
        bf16* ad = As + bi * 4096 + (wave * 16) * 64;
        gld_lds16(aptr[0] + aoff, ad);
        gld_lds16(aptr[1] + aoff, ad + 8 * 64);
        bf16* bd = Bs + bi * 16384 + (wave * 64) * 64;
#pragma unroll
        for (int u = 0; u < 8; ++u)
            gld_lds16(bptr0 + (size_t)u * 8 * K + boff, bd + u * 8 * 64);
    };

    f32x4 acc[2][8] = {};
    auto COMPUTE = [&](int bi) {
        const bf16* ab = As + bi * 4096;
        const bf16* bb = Bs + bi * 16384;
#pragma unroll
        for (int ks = 0; ks < 2; ++ks) {
            int ch = ((ks * 4 + fq) ^ (fr & 7)) * 8;
            bf16x8 af[2];
#pragma unroll
            for (int mi = 0; mi < 2; ++mi) af[mi] = *(const bf16x8*)&ab[(wm * 32 + mi * 16 + fr) * 64 + ch];
            bf16x8 bv[8];
#pragma unroll
            for (int ni = 0; ni < 8; ++ni) bv[ni] = *(const bf16x8*)&bb[(wn * 128 + ni * 16 + fr) * 64 + ch];
#pragma unroll
            for (int mi = 0; mi < 2; ++mi)
#pragma unroll
                for (int ni = 0; ni < 8; ++ni)
                    acc[mi][ni] = __builtin_amdgcn_mfma_f32_16x16x32_bf16(af[mi], bv[ni], acc[mi][ni], 0, 0, 0);
        }
    };

    const int nk = K >> 6;
    STAGE(0, 0);
    VMCNT0();
    BAR();
    int cur = 0;
    for (int kt = 0; kt < nk - 1; ++kt) {
        STAGE(cur ^ 1, kt + 1);
        COMPUTE(cur);
        VMCNT0();
        BAR();
        cur ^= 1;
    }
    COMPUTE(cur);

    // ---- epilogue in acc-space: bias (+res) (+gelu) ----
    float bvv[8];
#pragma unroll
    for (int ni = 0; ni < 8; ++ni) bvv[ni] = bias[wn * 128 + ni * 16 + fr] * bscale;
#pragma unroll
    for (int mi = 0; mi < 2; ++mi)
#pragma unroll
        for (int ni = 0; ni < 8; ++ni)
#pragma unroll
            for (int r = 0; r < 4; ++r) {
                float x = acc[mi][ni][r] + bvv[ni];
                if (MODE == M_WPLN) {
                    int prow = m0 + wm * 32 + mi * 16 + fq * 4 + r;
                    int col = wn * 128 + ni * 16 + fr;
                    x += (float)res[(size_t)prow * 256 + col];
                }
                if (MODE == M_GELU) x = 0.5f * x * (1.0f + erff(x * 0.70710678118f));
                acc[mi][ni][r] = x;
            }

    // ---- LN stats (M_LN2, M_WPLN) ----
    float mean_[2][4], rstd_[2][4];
    if (MODE == M_LN2 || MODE == M_WPLN) {
        BAR();   // all waves done reading As/Bs
#pragma unroll
        for (int mi = 0; mi < 2; ++mi)
#pragma unroll
            for (int r = 0; r < 4; ++r) {
                float s = 0.0f, ss = 0.0f;
#pragma unroll
                for (int ni = 0; ni < 8; ++ni) {
                    float x = acc[mi][ni][r];
                    s += x; ss += x * x;
                }
#pragma unroll
                for (int msk = 1; msk <= 8; msk <<= 1) {
                    s += __shfl_xor(s, msk);
                    ss += __shfl_xor(ss, msk);
                }
                if (fr == 0) {
                    int row = wm * 32 + mi * 16 + fq * 4 + r;
                    lnb[wn * 128 + row] = s;
                    lnb[wn * 128 + 64 + row] = ss;
                }
            }
        BAR();
#pragma unroll
        for (int mi = 0; mi < 2; ++mi)
#pragma unroll
            for (int r = 0; r < 4; ++r) {
                int row = wm * 32 + mi * 16 + fq * 4 + r;
                float s = lnb[row] + lnb[128 + row];
                float ss = lnb[64 + row] + lnb[192 + row];
                float mean = s * (1.0f / CH);
                float var = ss * (1.0f / CH) - mean * mean;
                mean_[mi][r] = mean;
                rstd_[mi][r] = rsqrtf(var + 1e-5f);
            }
    } else {
        BAR();   // protect smem before T writes
    }

    // ---- write x (or x-hat for LN2) to T ----
#pragma unroll
    for (int mi = 0; mi < 2; ++mi)
#pragma unroll
        for (int ni = 0; ni < 8; ++ni)
#pragma unroll
            for (int r = 0; r < 4; ++r) {
                int row = wm * 32 + mi * 16 + fq * 4 + r;
                int col = wn * 128 + ni * 16 + fr;
                float x = acc[mi][ni][r];
                if (MODE == M_LN2) x = (x - mean_[mi][r]) * rstd_[mi][r];
                T[row * 257 + col] = x;
            }
    BAR();

    // ---- store phase (coalesced) ----
    if (MODE == M_NCHW) {
        int c = tid;                             // output channel 0..255
        int b = m0 / IMG2, p0 = m0 - b * IMG2;
        float* outp = outf + ((size_t)(b * CH + c)) * IMG2 + p0;
        const bf16* rp = res + (size_t)m0 * 256 + c;
#pragma unroll
        for (int g = 0; g < 16; ++g) {
            f32x4 v;
#pragma unroll
            for (int e = 0; e < 4; ++e)
                v[e] = T[(g * 4 + e) * 257 + c] + (float)rp[(size_t)(g * 4 + e) * 256];
            *(f32x4*)(outp + g * 4) = v;
        }
    } else {
        int row = tid & 63, qd = tid >> 6;       // each wave stores one 64-col quarter
        int cb = qd * 64;
        if (MODE == M_DENSE || MODE == M_GELU) {
            bf16* op = out0 + (size_t)(m0 + row) * ldo0 + cb;
#pragma unroll
            for (int g = 0; g < 8; ++g) {
                bf16x8 o;
#pragma unroll
                for (int e = 0; e < 8; ++e) o[e] = (bf16)T[row * 257 + cb + g * 8 + e];
                *(bf16x8*)(op + g * 8) = o;
            }
        } else if (MODE == M_LN2) {
            bf16* op0 = out0 + (size_t)(m0 + row) * 256 + cb;
            bf16* op1 = out1 + (size_t)(m0 + row) * 256 + cb;
#pragma unroll
            for (int g = 0; g < 8; ++g) {
                bf16x8 o0, o1;
#pragma unroll
                for (int e = 0; e < 8; ++e) {
                    int c = cb + g * 8 + e;
                    float xh = T[row * 257 + c];
                    o0[e] = (bf16)(xh * lnw0[c] + lnb0[c]);
                    o1[e] = (bf16)(xh * lnw1[c] + lnb1[c]);
                }
                *(bf16x8*)(op0 + g * 8) = o0;
                *(bf16x8*)(op1 + g * 8) = o1;
            }
        } else if (MODE == M_WPLN) {
            float s = lnb[row] + lnb[128 + row];
            float ss = lnb[64 + row] + lnb[192 + row];
            float mean = s * (1.0f / CH);
            float rstd = rsqrtf(ss * (1.0f / CH) - mean * mean + 1e-5f);
            bf16* op0 = out0 + (size_t)(m0 + row) * 256 + cb;   // ATT (raw)
            bf16* op1 = out1 + (size_t)(m0 + row) * 256 + cb;   // H (normalized)
#pragma unroll
            for (int g = 0; g < 8; ++g) {
                bf16x8 o0, o1;
#pragma unroll
                for (int e = 0; e < 8; ++e) {
                    int c = cb + g * 8 + e;
                    float x = T[row * 257 + c];
                    o0[e] = (bf16)x;
                    o1[e] = (bf16)((x - mean) * rstd * lnw0[c] + lnb0[c]);
                }
                *(bf16x8*)(op0 + g * 8) = o0;
                *(bf16x8*)(op1 + g * 8) = o1;
            }
        }
    }
}

// ---------------- wrapper kernels ----------------
__global__ __launch_bounds__(256) void conv_kernel(
    const bf16* padq, const bf16* padkv, const bf16* cw1, const bf16* cw2,
    const float* c1b, const float* c3b,
    bf16* qn, bf16* kvn, bf16* x3,
    const float* l1w, const float* l1b, const float* l10w, const float* l10b) {
    __shared__ char sm[81920];
    if (blockIdx.y == 0)
        gemm_core<1, M_LN2>(sm, padq, cw1, c1b, 1.0f, nullptr, qn, 256, kvn, nullptr,
                            l1w, l1b, l10w, l10b, 576);
    else
        gemm_core<1, M_DENSE>(sm, padkv, cw2, c3b, 1.0f, nullptr, x3, 256, nullptr, nullptr,
                              nullptr, nullptr, nullptr, nullptr, 576);
}

__global__ __launch_bounds__(256) void qkv_kernel(
    const bf16* qnp, const bf16* kvnp, const bf16* wqt, const bf16* wkvt,
    const float* bq, const float* bkv, bf16* q, bf16* kv) {
    __shared__ char sm[81920];
    int by = blockIdx.y;
    const bf16* A = by ? kvnp : qnp;
    const bf16* B = by ? (wkvt + (size_t)(by - 1) * 65536) : wqt;
    const float* bias = by ? (bkv + (by - 1) * 256) : bq;
    float bsc = by ? 1.0f : SCQ;
    bf16* out = by ? (kv + (by - 1) * 256) : q;
    int ldo = by ? 512 : 256;
    gemm_core<0, M_DENSE>(sm, A, B, bias, bsc, nullptr, out, ldo, nullptr, nullptr,
                          nullptr, nullptr, nullptr, nullptr, 256);
}

__global__ __launch_bounds__(256) void wp_kernel(
    const bf16* ao, const bf16* wpt, const float* bp, const bf16* x3,
    bf16* att, bf16* h, const float* l3w, const float* l3b) {
    __shared__ char sm[81920];
    gemm_core<0, M_WPLN>(sm, ao, wpt, bp, 1.0f, x3, att, 256, h, nullptr,
                         l3w, l3b, nullptr, nullptr, 256);
}

__global__ __launch_bounds__(256) void fc1_kernel(
    const bf16* h, const bf16* wf1, const float* f1b, bf16* m1) {
    __shared__ char sm[81920];
    int by = blockIdx.y;
    gemm_core<0, M_GELU>(sm, h, wf1 + (size_t)by * 65536, f1b + by * 256, 1.0f, nullptr,
                         m1 + by * 256, 512, nullptr, nullptr,
                         nullptr, nullptr, nullptr, nullptr, 256);
}

__global__ __launch_bounds__(256) void fc2_kernel(
    const bf16* m1, const bf16* wf2, const float* f2b, const bf16* att, float* out) {
    __shared__ char sm[81920];
    gemm_core<0, M_NCHW>(sm, m1, wf2, f2b, 1.0f, att, nullptr, 0, nullptr, out,
                         nullptr, nullptr, nullptr, nullptr, 512);
}

// ---------------- neighborhood attention (3x3 window, 8 heads, hd=32) ----------------
__global__ __launch_bounds__(256) void attn_kernel(const bf16* __restrict__ q, const bf16* __restrict__ kv,
                                                   const float* __restrict__ rpb, bf16* __restrict__ out) {
    int idx = blockIdx.x * 256 + threadIdx.x;   // 25088*8 total
    int h = idx & 7, p = idx >> 3;
    int b = p / IMG2;
    int rem = p - b * IMG2;
    int i = rem / IMG, j = rem - i * IMG;
    int si = i - 1; if (si < 0) si = 0; if (si > IMG - 3) si = IMG - 3;
    int sj = j - 1; if (sj < 0) sj = 0; if (sj > IMG - 3) sj = IMG - 3;
    int pi = i - si, pj = j - sj;

    float qv[32];
    {
        const bf16x8* qp = (const bf16x8*)(q + (size_t)p * CH + h * 32);
#pragma unroll
        for (int g = 0; g < 4; ++g) {
            bf16x8 t = qp[g];
#pragma unroll
            for (int e = 0; e < 8; ++e) qv[g * 8 + e] = (float)t[e];
        }
    }
    float logits[9];
#pragma unroll
    for (int a = 0; a < 3; ++a) {
#pragma unroll
        for (int bb = 0; bb < 3; ++bb) {
            int pn = (b * IMG + (si + a)) * IMG + (sj + bb);
            const bf16x8* kp = (const bf16x8*)(kv + (size_t)pn * 512 + h * 32);
            float s = 0.0f;
#pragma unroll
            for (int g = 0; g < 4; ++g) {
                bf16x8 t = kp[g];
#pragma unroll
                for (int e = 0; e < 8; ++e) s += qv[g * 8 + e] * (float)t[e];
            }
            logits[a * 3 + bb] = s + rpb[(h * 5 + (a - pi + 2)) * 5 + (bb - pj + 2)];
        }
    }
    float mx = logits[0];
#pragma unroll
    for (int n = 1; n < 9; ++n) mx = fmaxf(mx, logits[n]);
    float den = 0.0f;
#pragma unroll
    for (int n = 0; n < 9; ++n) { logits[n] = expf(logits[n] - mx); den += logits[n]; }
    float inv = 1.0f / den;
    float o[32] = {};
#pragma unroll
    for (int a = 0; a < 3; ++a) {
#pragma unroll
        for (int bb = 0; bb < 3; ++bb) {
            int pn = (b * IMG + (si + a)) * IMG + (sj + bb);
            float wgt = logits[a * 3 + bb] * inv;
            const bf16x8* vp = (const bf16x8*)(kv + (size_t)pn * 512 + 256 + h * 32);
#pragma unroll
            for (int g = 0; g < 4; ++g) {
                bf16x8 t = vp[g];
#pragma unroll
                for (int e = 0; e < 8; ++e) o[g * 8 + e] += wgt * (float)t[e];
            }
        }
    }
    bf16* op = out + (size_t)p * CH + h * 32;
#pragma unroll
    for (int g = 0; g < 4; ++g) {
        bf16x8 t;
#pragma unroll
        for (int e = 0; e < 8; ++e) t[e] = (bf16)o[g * 8 + e];
        *(bf16x8*)(op + g * 8) = t;
    }
}

extern "C" void kernel_launch(void* const* d_in, const int* in_sizes, int n_in,
                              void* d_out, int out_size, void* d_ws, size_t ws_size,
                              hipStream_t stream) {
    (void)in_sizes; (void)n_in; (void)out_size; (void)ws_size;
    const float* xq    = (const float*)d_in[0];
    const float* xkv   = (const float*)d_in[1];
    const float* c1w   = (const float*)d_in[2];
    const float* c1b   = (const float*)d_in[3];
    const float* c3w   = (const float*)d_in[4];
    const float* c3b   = (const float*)d_in[5];
    const float* ln1w  = (const float*)d_in[6];
    const float* ln1b  = (const float*)d_in[7];
    const float* ln10w = (const float*)d_in[8];
    const float* ln10b = (const float*)d_in[9];
    const float* ln3w  = (const float*)d_in[10];
    const float* ln3b  = (const float*)d_in[11];
    const float* wq    = (const float*)d_in[12];
    const float* bq    = (const float*)d_in[13];
    const float* wkv   = (const float*)d_in[14];
    const float* bkv   = (const float*)d_in[15];
    const float* rpb   = (const float*)d_in[16];
    const float* wp    = (const float*)d_in[17];
    const float* bp    = (const float*)d_in[18];
    const float* f1w   = (const float*)d_in[19];
    const float* f1b   = (const float*)d_in[20];
    const float* f2w   = (const float*)d_in[21];
    const float* f2b   = (const float*)d_in[22];
    float* out = (float*)d_out;

    char* ws = (char*)d_ws;
    bf16* PADQ  = (bf16*)(ws + 0);           // 3,326,976
    bf16* PADKV = (bf16*)(ws + 3326976);     // 3,326,976
    bf16* CW1   = (bf16*)(ws + 6653952);     //   294,912
    bf16* CW2   = (bf16*)(ws + 6948864);     //   294,912
    bf16* WQT   = (bf16*)(ws + 7243776);     //   131,072
    bf16* WKVT  = (bf16*)(ws + 7374848);     //   262,144
    bf16* WPT   = (bf16*)(ws + 7636992);     //   131,072
    bf16* WF1   = (bf16*)(ws + 7768064);     //   262,144
    bf16* WF2   = (bf16*)(ws + 8030208);     //   262,144
    bf16* QN    = (bf16*)(ws + 8292352);     // 12,845,056
    bf16* KVN   = (bf16*)(ws + 21137408);    // 12,845,056
    bf16* Q     = (bf16*)(ws + 33982464);    // 12,845,056
    bf16* KV    = (bf16*)(ws + 46827520);    // 25,690,112
    bf16* AO    = (bf16*)(ws + 72517632);    // 12,845,056
    bf16* X3    = (bf16*)(ws + 85362688);    // 12,845,056
    bf16* ATT   = (bf16*)(ws + 98207744);    // 12,845,056
    bf16* H     = (bf16*)(ws + 111052800);   // 12,845,056
    bf16* M1    = (bf16*)(ws + 123897856);   // 25,690,112 -> total 149,587,968

    prep_kernel<<<3072, 256, 0, stream>>>(xq, xkv, PADQ, PADKV, c1w, c3w, CW1, CW2,
                                          wq, WQT, wkv, WKVT, wp, WPT, f1w, WF1, f2w, WF2);
    conv_kernel<<<dim3(392, 2), 256, 0, stream>>>(PADQ, PADKV, CW1, CW2, c1b, c3b,
                                                  QN, KVN, X3, ln1w, ln1b, ln10w, ln10b);
    qkv_kernel<<<dim3(392, 3), 256, 0, stream>>>(QN, KVN, WQT, WKVT, bq, bkv, Q, KV);
    attn_kernel<<<784, 256, 0, stream>>>(Q, KV, rpb, AO);
    wp_kernel<<<392, 256, 0, stream>>>(AO, WPT, bp, X3, ATT, H, ln3w, ln3b);
    fc1_kernel<<<dim3(392, 2), 256, 0, stream>>>(H, WF1, f1b, M1);
    fc2_kernel<<<392, 256, 0, stream>>>(M1, WF2, f2b, ATT, out);
}